// Round 1
// baseline (362.550 us; speedup 1.0000x reference)
//
#include <hip/hip_runtime.h>
#include <hip/hip_bf16.h>
#include <stdint.h>

#define EMBED 1024
#define NHEAD 16
#define DKD   64
#define BATCH 2
#define SEQ   2048
#define MROWS (BATCH*SEQ)   // 4096

typedef __attribute__((ext_vector_type(8))) short bf16x8;
typedef __attribute__((ext_vector_type(4))) float f32x4;
typedef unsigned short u16;
typedef unsigned int   u32;

__device__ inline u16 f2bf(float f) {
  union { float f; u32 u; } v; v.f = f;
  u32 u = v.u;
  return (u16)((u + 0x7fffu + ((u >> 16) & 1u)) >> 16);  // RNE
}

__device__ inline void gload_lds16(const u16* g, u16* l) {
  __builtin_amdgcn_global_load_lds(
      (const __attribute__((address_space(1))) u32*)(const void*)g,
      (__attribute__((address_space(3))) u32*)(void*)l, 16, 0, 0);
}

// ---------------- cast fp32 -> bf16 ----------------
__global__ __launch_bounds__(256) void cast_kernel(const float* __restrict__ in,
                                                   u16* __restrict__ out, int n4) {
  int i = blockIdx.x * blockDim.x + threadIdx.x;
  int stride = gridDim.x * blockDim.x;
  for (int idx = i; idx < n4; idx += stride) {
    float4 f = ((const float4*)in)[idx];
    ushort4 o;
    o.x = f2bf(f.x); o.y = f2bf(f.y); o.z = f2bf(f.z); o.w = f2bf(f.w);
    ((ushort4*)out)[idx] = o;
  }
}

// ---------------- B^T GEMM: C[m,n] = sum_k A[m,k]*B[n,k] ----------------
// A: [M,K] bf16 row-major, B: [N,K] bf16 row-major.
// EPI 0: bf16 -> [b,h,s,dk]   (Q,K heads)
// EPI 1: bf16 -> [b,h,dk,s]   (V transposed per head)
// EPI 2: f32  -> [M,N] row-major (final output)
template <int EPI>
__global__ __launch_bounds__(256)
void gemm_bt(const u16* __restrict__ A, const u16* __restrict__ B,
             void* __restrict__ Cout, int M, int N, int K) {
  __shared__ u16 As[128 * 32];
  __shared__ u16 Bs[128 * 32];
  const int t = threadIdx.x;
  const int w = t >> 6;
  const int l = t & 63;
  const int lr = l & 15, lg = l >> 4;
  const int m0 = blockIdx.x * 128;
  const int n0 = blockIdx.y * 128;
  const int wr = (w >> 1) * 64, wc = (w & 1) * 64;

  f32x4 acc[4][4] = {};

  const int srow = t >> 2;             // 0..63
  const int scol = (t & 3) * 8;        // 0,8,16,24
  const u16* Ag = A + (size_t)(m0 + srow) * K + scol;
  const u16* Bg = B + (size_t)(n0 + srow) * K + scol;
  u16* AsW = As + w * 512;             // wave-uniform LDS base (lane*16B order)
  u16* BsW = Bs + w * 512;
  const size_t rowstep = (size_t)64 * K;

  for (int k0 = 0; k0 < K; k0 += 32) {
    gload_lds16(Ag + k0,            AsW);
    gload_lds16(Ag + k0 + rowstep,  AsW + 64 * 32);
    gload_lds16(Bg + k0,            BsW);
    gload_lds16(Bg + k0 + rowstep,  BsW + 64 * 32);
    __syncthreads();
    bf16x8 a[4], b[4];
#pragma unroll
    for (int r = 0; r < 4; r++)
      a[r] = *(const bf16x8*)(As + (wr + r * 16 + lr) * 32 + 8 * lg);
#pragma unroll
    for (int c = 0; c < 4; c++)
      b[c] = *(const bf16x8*)(Bs + (wc + c * 16 + lr) * 32 + 8 * lg);
#pragma unroll
    for (int r = 0; r < 4; r++)
#pragma unroll
      for (int c = 0; c < 4; c++)
        acc[r][c] = __builtin_amdgcn_mfma_f32_16x16x32_bf16(a[r], b[c], acc[r][c], 0, 0, 0);
    __syncthreads();
  }

#pragma unroll
  for (int r = 0; r < 4; r++)
#pragma unroll
    for (int c = 0; c < 4; c++)
#pragma unroll
      for (int j = 0; j < 4; j++) {
        int m = m0 + wr + r * 16 + lg * 4 + j;   // row
        int n = n0 + wc + c * 16 + lr;           // col
        float vv = acc[r][c][j];
        if (EPI == 2) {
          ((float*)Cout)[(size_t)m * N + n] = vv;
        } else {
          int b_ = m >> 11, s_ = m & 2047;       // m = b*SEQ + s
          int h_ = n >> 6,  d_ = n & 63;         // n = h*DK + d
          if (EPI == 0)
            ((u16*)Cout)[(((size_t)(b_ * NHEAD + h_) * SEQ + s_) << 6) + d_] = f2bf(vv);
          else
            ((u16*)Cout)[((size_t)(b_ * NHEAD + h_) * DKD + d_) * SEQ + s_] = f2bf(vv);
        }
      }
}

// ---------------- flash attention ----------------
// Qh,Kh: [B,H,S,DK] bf16; Vt: [B,H,DK,S] bf16; Xo: [B,S,E] bf16 (heads merged)
__global__ __launch_bounds__(256)
void attn_kernel(const u16* __restrict__ Qh, const u16* __restrict__ Kh,
                 const u16* __restrict__ Vt, u16* __restrict__ Xo) {
  __shared__ u16 P_lds[4][16][40];   // per-wave P tile, padded 32->40 (80B rows, 16B aligned)
  const int t = threadIdx.x, w = t >> 6, l = t & 63;
  const int lr = l & 15, lg = l >> 4;
  const int qblk = blockIdx.x;          // S/64 blocks
  const int bh = blockIdx.y;            // b*NHEAD + h
  const int b_ = bh >> 4, h_ = bh & 15;
  const size_t base = (size_t)bh * SEQ * DKD;

  const int qrow = qblk * 64 + w * 16 + lr;
  bf16x8 qf[2];
  qf[0] = *(const bf16x8*)(Qh + base + (size_t)qrow * DKD + 8 * lg);
  qf[1] = *(const bf16x8*)(Qh + base + (size_t)qrow * DKD + 32 + 8 * lg);
  const u16* Kb = Kh + base;
  const u16* Vb = Vt + base;            // [DK][SEQ]

  f32x4 acc[4] = {};                    // 16q x 64d output (4 col-blocks)
  float mrow[4], lrow[4];
#pragma unroll
  for (int j = 0; j < 4; j++) { mrow[j] = -1e30f; lrow[j] = 0.f; }

  for (int kt = 0; kt < SEQ / 32; kt++) {
    f32x4 s[2] = {};
#pragma unroll
    for (int c = 0; c < 2; c++)
#pragma unroll
      for (int ks = 0; ks < 2; ks++) {
        bf16x8 kf = *(const bf16x8*)(Kb + (size_t)(kt * 32 + c * 16 + lr) * DKD + ks * 32 + 8 * lg);
        s[c] = __builtin_amdgcn_mfma_f32_16x16x32_bf16(qf[ks], kf, s[c], 0, 0, 0);
      }
    // online softmax (scale 1/sqrt(64) = 0.125)
    float pm[4];
#pragma unroll
    for (int j = 0; j < 4; j++) {
      float a0 = s[0][j] * 0.125f, a1 = s[1][j] * 0.125f;
      s[0][j] = a0; s[1][j] = a1;
      pm[j] = fmaxf(a0, a1);
    }
#pragma unroll
    for (int off = 1; off < 16; off <<= 1)
#pragma unroll
      for (int j = 0; j < 4; j++)
        pm[j] = fmaxf(pm[j], __shfl_xor(pm[j], off, 64));
    float alpha[4], psum[4];
#pragma unroll
    for (int j = 0; j < 4; j++) {
      float mnew = fmaxf(mrow[j], pm[j]);
      alpha[j] = __expf(mrow[j] - mnew);
      mrow[j] = mnew;
      float p0 = __expf(s[0][j] - mnew), p1 = __expf(s[1][j] - mnew);
      s[0][j] = p0; s[1][j] = p1;
      psum[j] = p0 + p1;
    }
#pragma unroll
    for (int off = 1; off < 16; off <<= 1)
#pragma unroll
      for (int j = 0; j < 4; j++)
        psum[j] += __shfl_xor(psum[j], off, 64);
#pragma unroll
    for (int j = 0; j < 4; j++) lrow[j] = lrow[j] * alpha[j] + psum[j];
#pragma unroll
    for (int n = 0; n < 4; n++)
#pragma unroll
      for (int j = 0; j < 4; j++) acc[n][j] *= alpha[j];
    // P (acc layout) -> LDS -> A-fragment layout
#pragma unroll
    for (int c = 0; c < 2; c++)
#pragma unroll
      for (int j = 0; j < 4; j++)
        P_lds[w][lg * 4 + j][c * 16 + lr] = f2bf(s[c][j]);
    bf16x8 pf = *(const bf16x8*)(&P_lds[w][lr][8 * lg]);
#pragma unroll
    for (int n = 0; n < 4; n++) {
      bf16x8 vf = *(const bf16x8*)(Vb + (size_t)(n * 16 + lr) * SEQ + kt * 32 + 8 * lg);
      acc[n] = __builtin_amdgcn_mfma_f32_16x16x32_bf16(pf, vf, acc[n], 0, 0, 0);
    }
  }
  // epilogue: rows q = qblk*64 + w*16 + lg*4+j, col d = n*16+lr
#pragma unroll
  for (int n = 0; n < 4; n++)
#pragma unroll
    for (int j = 0; j < 4; j++) {
      int q = qblk * 64 + w * 16 + lg * 4 + j;
      float ov = acc[n][j] / lrow[j];
      Xo[((size_t)b_ * SEQ + q) * EMBED + h_ * DKD + n * 16 + lr] = f2bf(ov);
    }
}

extern "C" void kernel_launch(void* const* d_in, const int* in_sizes, int n_in,
                              void* d_out, int out_size, void* d_ws, size_t ws_size,
                              hipStream_t stream) {
  const float* q  = (const float*)d_in[0];
  const float* k  = (const float*)d_in[1];
  const float* v  = (const float*)d_in[2];
  const float* Wq = (const float*)d_in[3];
  const float* Wk = (const float*)d_in[4];
  const float* Wv = (const float*)d_in[5];
  const float* Wo = (const float*)d_in[6];

  char* ws = (char*)d_ws;
  const size_t SZ_X = (size_t)MROWS * EMBED * 2;   // 8 MiB
  const size_t SZ_W = (size_t)EMBED * EMBED * 2;   // 2 MiB
  u16* qbf  = (u16*)(ws);
  u16* kbf  = (u16*)(ws + SZ_X);
  u16* vbf  = (u16*)(ws + 2 * SZ_X);
  u16* wqb  = (u16*)(ws + 3 * SZ_X);
  u16* wkb  = (u16*)(ws + 3 * SZ_X + SZ_W);
  u16* wvb  = (u16*)(ws + 3 * SZ_X + 2 * SZ_W);
  u16* wob  = (u16*)(ws + 3 * SZ_X + 3 * SZ_W);
  u16* Qh   = (u16*)(ws + 3 * SZ_X + 4 * SZ_W);
  u16* Kh   = (u16*)(ws + 4 * SZ_X + 4 * SZ_W);
  u16* Vt   = (u16*)(ws + 5 * SZ_X + 4 * SZ_W);
  u16* Xcat = (u16*)(ws + 6 * SZ_X + 4 * SZ_W);    // total 64 MiB

  const int nX4 = MROWS * EMBED / 4;
  const int nW4 = EMBED * EMBED / 4;
  cast_kernel<<<2048, 256, 0, stream>>>(q,  qbf, nX4);
  cast_kernel<<<2048, 256, 0, stream>>>(k,  kbf, nX4);
  cast_kernel<<<2048, 256, 0, stream>>>(v,  vbf, nX4);
  cast_kernel<<<1024, 256, 0, stream>>>(Wq, wqb, nW4);
  cast_kernel<<<1024, 256, 0, stream>>>(Wk, wkb, nW4);
  cast_kernel<<<1024, 256, 0, stream>>>(Wv, wvb, nW4);
  cast_kernel<<<1024, 256, 0, stream>>>(Wo, wob, nW4);

  dim3 gg(MROWS / 128, EMBED / 128);
  gemm_bt<0><<<gg, 256, 0, stream>>>(qbf, wqb, Qh, MROWS, EMBED, EMBED);
  gemm_bt<0><<<gg, 256, 0, stream>>>(kbf, wkb, Kh, MROWS, EMBED, EMBED);
  gemm_bt<1><<<gg, 256, 0, stream>>>(vbf, wvb, Vt, MROWS, EMBED, EMBED);

  attn_kernel<<<dim3(SEQ / 64, BATCH * NHEAD), 256, 0, stream>>>(Qh, Kh, Vt, Xcat);

  gemm_bt<2><<<gg, 256, 0, stream>>>(Xcat, wob, d_out, MROWS, EMBED, EMBED);
}

// Round 2
// 306.462 us; speedup vs baseline: 1.1830x; 1.1830x over previous
//
#include <hip/hip_runtime.h>
#include <hip/hip_bf16.h>
#include <stdint.h>

#define EMBED 1024
#define NHEAD 16
#define DKD   64
#define BATCH 2
#define SEQ   2048
#define MROWS (BATCH*SEQ)   // 4096

typedef __attribute__((ext_vector_type(8))) short bf16x8;
typedef __attribute__((ext_vector_type(4))) float f32x4;
typedef unsigned short u16;
typedef unsigned int   u32;

__device__ inline u16 f2bf(float f) {
  return __builtin_bit_cast(u16, __float2bfloat16(f));  // single v_cvt, RNE
}

__device__ inline void gload_lds16(const u16* g, u16* l) {
  __builtin_amdgcn_global_load_lds(
      (const __attribute__((address_space(1))) u32*)(const void*)g,
      (__attribute__((address_space(3))) u32*)(void*)l, 16, 0, 0);
}

// ---------------- fused cast fp32 -> bf16 (all 7 tensors, 1 launch) --------
__global__ __launch_bounds__(256) void cast_all(
    const float* __restrict__ s0, const float* __restrict__ s1,
    const float* __restrict__ s2, const float* __restrict__ s3,
    const float* __restrict__ s4, const float* __restrict__ s5,
    const float* __restrict__ s6,
    u16* __restrict__ d0, u16* __restrict__ d1, u16* __restrict__ d2,
    u16* __restrict__ d3, u16* __restrict__ d4, u16* __restrict__ d5,
    u16* __restrict__ d6) {
  const int y = blockIdx.y;
  const float* s; u16* d; int n4;
  switch (y) {
    case 0: s = s0; d = d0; n4 = MROWS*EMBED/4; break;
    case 1: s = s1; d = d1; n4 = MROWS*EMBED/4; break;
    case 2: s = s2; d = d2; n4 = MROWS*EMBED/4; break;
    case 3: s = s3; d = d3; n4 = EMBED*EMBED/4; break;
    case 4: s = s4; d = d4; n4 = EMBED*EMBED/4; break;
    case 5: s = s5; d = d5; n4 = EMBED*EMBED/4; break;
    default: s = s6; d = d6; n4 = EMBED*EMBED/4; break;
  }
  int i = blockIdx.x * 256 + threadIdx.x;
  int stride = gridDim.x * 256;
  for (int idx = i; idx < n4; idx += stride) {
    float4 f = ((const float4*)s)[idx];
    ushort4 o;
    o.x = f2bf(f.x); o.y = f2bf(f.y); o.z = f2bf(f.z); o.w = f2bf(f.w);
    ((ushort4*)d)[idx] = o;
  }
}

// ---------------- fused QKV projection GEMM (B^T), BM=128, grid.z selects --
// C[m,n] = sum_k A[m,k]*B[n,k];  z=0,1 -> [b,h,s,dk] bf16; z=2 -> [b,h,dk,s]
__global__ __launch_bounds__(256)
void gemm_qkv(const u16* __restrict__ A0, const u16* __restrict__ A1,
              const u16* __restrict__ A2, const u16* __restrict__ B0,
              const u16* __restrict__ B1, const u16* __restrict__ B2,
              u16* __restrict__ C0, u16* __restrict__ C1, u16* __restrict__ C2) {
  constexpr int K = EMBED;
  __shared__ u16 As[128 * 32];
  __shared__ u16 Bs[128 * 32];
  const int z = blockIdx.z;
  const u16* A = (z == 0) ? A0 : (z == 1) ? A1 : A2;
  const u16* B = (z == 0) ? B0 : (z == 1) ? B1 : B2;
  u16* C       = (z == 0) ? C0 : (z == 1) ? C1 : C2;

  const int t = threadIdx.x;
  const int w = t >> 6, l = t & 63;
  const int lr = l & 15, lg = l >> 4;
  const int m0 = blockIdx.x * 128;
  const int n0 = blockIdx.y * 128;
  const int wr = (w >> 1) * 64, wc = (w & 1) * 64;

  f32x4 acc[4][4] = {};

  const int srow = t >> 2;
  const int scol = (t & 3) * 8;
  const u16* Ag = A + (size_t)(m0 + srow) * K + scol;
  const u16* Bg = B + (size_t)(n0 + srow) * K + scol;
  u16* AsW = As + w * 512;
  u16* BsW = Bs + w * 512;
  const size_t rowstep = (size_t)64 * K;

  for (int k0 = 0; k0 < K; k0 += 32) {
    gload_lds16(Ag + k0,           AsW);
    gload_lds16(Ag + k0 + rowstep, AsW + 64 * 32);
    gload_lds16(Bg + k0,           BsW);
    gload_lds16(Bg + k0 + rowstep, BsW + 64 * 32);
    __syncthreads();
    bf16x8 a[4], b[4];
#pragma unroll
    for (int r = 0; r < 4; r++)
      a[r] = *(const bf16x8*)(As + (wr + r * 16 + lr) * 32 + 8 * lg);
#pragma unroll
    for (int c = 0; c < 4; c++)
      b[c] = *(const bf16x8*)(Bs + (wc + c * 16 + lr) * 32 + 8 * lg);
#pragma unroll
    for (int r = 0; r < 4; r++)
#pragma unroll
      for (int c = 0; c < 4; c++)
        acc[r][c] = __builtin_amdgcn_mfma_f32_16x16x32_bf16(a[r], b[c], acc[r][c], 0, 0, 0);
    __syncthreads();
  }

#pragma unroll
  for (int r = 0; r < 4; r++)
#pragma unroll
    for (int c = 0; c < 4; c++)
#pragma unroll
      for (int j = 0; j < 4; j++) {
        int m = m0 + wr + r * 16 + lg * 4 + j;
        int n = n0 + wc + c * 16 + lr;
        int b_ = m >> 11, s_ = m & 2047;
        int h_ = n >> 6,  d_ = n & 63;
        u16 vv = f2bf(acc[r][c][j]);
        if (z == 2)
          C[((size_t)(b_ * NHEAD + h_) * DKD + d_) * SEQ + s_] = vv;   // V^T
        else
          C[(((size_t)(b_ * NHEAD + h_) * SEQ + s_) << 6) + d_] = vv;  // heads
      }
}

// ---------------- output GEMM (B^T), BM=64 x BN=128, fp32 out -------------
__global__ __launch_bounds__(256)
void gemm_out(const u16* __restrict__ A, const u16* __restrict__ B,
              float* __restrict__ C) {
  constexpr int K = EMBED, N = EMBED;
  __shared__ u16 As[64 * 32];
  __shared__ u16 Bs[128 * 32];
  const int t = threadIdx.x;
  const int w = t >> 6, l = t & 63;
  const int lr = l & 15, lg = l >> 4;
  const int m0 = blockIdx.x * 64;
  const int n0 = blockIdx.y * 128;
  const int wr = (w >> 1) * 32, wc = (w & 1) * 64;

  f32x4 acc[2][4] = {};

  const int srow = t >> 2;
  const int scol = (t & 3) * 8;
  const u16* Ag = A + (size_t)(m0 + srow) * K + scol;
  const u16* Bg = B + (size_t)(n0 + srow) * K + scol;
  u16* AsW = As + w * 512;
  u16* BsW = Bs + w * 512;
  const size_t rowstep = (size_t)64 * K;

  for (int k0 = 0; k0 < K; k0 += 32) {
    gload_lds16(Ag + k0,           AsW);
    gload_lds16(Bg + k0,           BsW);
    gload_lds16(Bg + k0 + rowstep, BsW + 64 * 32);
    __syncthreads();
    bf16x8 a[2], b[4];
#pragma unroll
    for (int r = 0; r < 2; r++)
      a[r] = *(const bf16x8*)(As + (wr + r * 16 + lr) * 32 + 8 * lg);
#pragma unroll
    for (int c = 0; c < 4; c++)
      b[c] = *(const bf16x8*)(Bs + (wc + c * 16 + lr) * 32 + 8 * lg);
#pragma unroll
    for (int r = 0; r < 2; r++)
#pragma unroll
      for (int c = 0; c < 4; c++)
        acc[r][c] = __builtin_amdgcn_mfma_f32_16x16x32_bf16(a[r], b[c], acc[r][c], 0, 0, 0);
    __syncthreads();
  }

#pragma unroll
  for (int r = 0; r < 2; r++)
#pragma unroll
    for (int c = 0; c < 4; c++)
#pragma unroll
      for (int j = 0; j < 4; j++) {
        int m = m0 + wr + r * 16 + lg * 4 + j;
        int n = n0 + wc + c * 16 + lr;
        C[(size_t)m * N + n] = acc[r][c][j];
      }
}

// ---------------- flash attention, KVBLK=64, K ping-pong prefetch ----------
// Qh,Kh: [B,H,S,DK] bf16; Vt: [B,H,DK,S] bf16; Xo: [B,S,E] bf16
__global__ __launch_bounds__(256)
void attn_kernel(const u16* __restrict__ Qh, const u16* __restrict__ Kh,
                 const u16* __restrict__ Vt, u16* __restrict__ Xo) {
  __shared__ u16 P_lds[4][16][72];   // 144B row stride = 9x16B (odd multiple)
  const int t = threadIdx.x, w = t >> 6, l = t & 63;
  const int lr = l & 15, lg = l >> 4;
  const int qblk = blockIdx.x;
  const int bh = blockIdx.y;
  const int b_ = bh >> 4, h_ = bh & 15;
  const size_t base = (size_t)bh * SEQ * DKD;
  constexpr int NT = SEQ / 64;                 // 32 kv tiles
  constexpr float C2 = 0.125f * 1.44269504089f; // scale * log2(e)

  const int qrow = qblk * 64 + w * 16 + lr;
  bf16x8 qf[2];
  qf[0] = *(const bf16x8*)(Qh + base + (size_t)qrow * DKD + 8 * lg);
  qf[1] = *(const bf16x8*)(Qh + base + (size_t)qrow * DKD + 32 + 8 * lg);

  const u16* kp = Kh + base + (size_t)lr * DKD + 8 * lg;  // +c*16*64 +ks*32 +kt*4096
  const u16* vp = Vt + base + (size_t)lr * SEQ + 8 * lg;  // +n*16*SEQ +ks*32 +kt*64

  f32x4 acc[4] = {};
  float m2[4], lsum[4];
#pragma unroll
  for (int j = 0; j < 4; j++) { m2[j] = -1e30f; lsum[j] = 0.f; }

  auto loadK = [&](bf16x8 (&kf)[4][2], int kt) {
    const u16* p = kp + (size_t)kt * (64 * DKD);
#pragma unroll
    for (int c = 0; c < 4; c++)
#pragma unroll
      for (int ks = 0; ks < 2; ks++)
        kf[c][ks] = *(const bf16x8*)(p + c * 16 * DKD + ks * 32);
  };

  auto body = [&](bf16x8 (&kc)[4][2], bf16x8 (&kn)[4][2], int kt) {
    // QK^T on current K tile (4 independent accumulation chains)
    f32x4 s[4] = {};
#pragma unroll
    for (int ks = 0; ks < 2; ks++)
#pragma unroll
      for (int c = 0; c < 4; c++)
        s[c] = __builtin_amdgcn_mfma_f32_16x16x32_bf16(qf[ks], kc[c][ks], s[c], 0, 0, 0);
    // issue V loads for this tile early (overlap softmax VALU)
    bf16x8 vf[4][2];
    {
      const u16* p = vp + kt * 64;
#pragma unroll
      for (int n = 0; n < 4; n++)
#pragma unroll
        for (int ks = 0; ks < 2; ks++)
          vf[n][ks] = *(const bf16x8*)(p + (size_t)n * 16 * SEQ + ks * 32);
    }
    // prefetch next K tile (overlaps softmax + PV)
    int ktn = (kt + 1 < NT) ? kt + 1 : kt;
    loadK(kn, ktn);

    // ---- base-2 online softmax over 64 kv cols ----
    float pm[4];
#pragma unroll
    for (int c = 0; c < 4; c++)
#pragma unroll
      for (int j = 0; j < 4; j++)
        s[c][j] *= C2;
#pragma unroll
    for (int j = 0; j < 4; j++)
      pm[j] = fmaxf(fmaxf(s[0][j], s[1][j]), fmaxf(s[2][j], s[3][j]));
#pragma unroll
    for (int off = 1; off < 16; off <<= 1)
#pragma unroll
      for (int j = 0; j < 4; j++)
        pm[j] = fmaxf(pm[j], __shfl_xor(pm[j], off, 64));
    // defer-max (T13): only rescale when the running max grew by > 8 (2^8 bound)
    int need = 0;
#pragma unroll
    for (int j = 0; j < 4; j++) need |= (pm[j] > m2[j] + 8.0f);
    if (__any(need)) {
#pragma unroll
      for (int j = 0; j < 4; j++) {
        float mn = fmaxf(m2[j], pm[j]);
        float al = __builtin_amdgcn_exp2f(m2[j] - mn);
        lsum[j] *= al;
        m2[j] = mn;
#pragma unroll
        for (int n = 0; n < 4; n++) acc[n][j] *= al;
      }
    }
    float ps[4] = {0.f, 0.f, 0.f, 0.f};
#pragma unroll
    for (int c = 0; c < 4; c++)
#pragma unroll
      for (int j = 0; j < 4; j++) {
        float p = __builtin_amdgcn_exp2f(s[c][j] - m2[j]);
        ps[j] += p;
        P_lds[w][lg * 4 + j][c * 16 + lr] = f2bf(p);
      }
#pragma unroll
    for (int off = 1; off < 16; off <<= 1)
#pragma unroll
      for (int j = 0; j < 4; j++)
        ps[j] += __shfl_xor(ps[j], off, 64);
#pragma unroll
    for (int j = 0; j < 4; j++) lsum[j] += ps[j];

    // ---- PV ----
    bf16x8 pf[2];
    pf[0] = *(const bf16x8*)(&P_lds[w][lr][8 * lg]);
    pf[1] = *(const bf16x8*)(&P_lds[w][lr][32 + 8 * lg]);
#pragma unroll
    for (int ks = 0; ks < 2; ks++)
#pragma unroll
      for (int n = 0; n < 4; n++)
        acc[n] = __builtin_amdgcn_mfma_f32_16x16x32_bf16(pf[ks], vf[n][ks], acc[n], 0, 0, 0);
  };

  bf16x8 kfA[4][2], kfB[4][2];
  loadK(kfA, 0);
  for (int kt = 0; kt < NT; kt += 2) {
    body(kfA, kfB, kt);
    body(kfB, kfA, kt + 1);
  }

#pragma unroll
  for (int j = 0; j < 4; j++) lsum[j] = 1.0f / lsum[j];
#pragma unroll
  for (int n = 0; n < 4; n++)
#pragma unroll
    for (int j = 0; j < 4; j++) {
      int q = qblk * 64 + w * 16 + lg * 4 + j;
      Xo[((size_t)b_ * SEQ + q) * EMBED + h_ * DKD + n * 16 + lr] =
          f2bf(acc[n][j] * lsum[j]);
    }
}

extern "C" void kernel_launch(void* const* d_in, const int* in_sizes, int n_in,
                              void* d_out, int out_size, void* d_ws, size_t ws_size,
                              hipStream_t stream) {
  const float* q  = (const float*)d_in[0];
  const float* k  = (const float*)d_in[1];
  const float* v  = (const float*)d_in[2];
  const float* Wq = (const float*)d_in[3];
  const float* Wk = (const float*)d_in[4];
  const float* Wv = (const float*)d_in[5];
  const float* Wo = (const float*)d_in[6];

  char* ws = (char*)d_ws;
  const size_t SZ_X = (size_t)MROWS * EMBED * 2;   // 8 MiB
  const size_t SZ_W = (size_t)EMBED * EMBED * 2;   // 2 MiB
  u16* qbf  = (u16*)(ws);
  u16* kbf  = (u16*)(ws + SZ_X);
  u16* vbf  = (u16*)(ws + 2 * SZ_X);
  u16* wqb  = (u16*)(ws + 3 * SZ_X);
  u16* wkb  = (u16*)(ws + 3 * SZ_X + SZ_W);
  u16* wvb  = (u16*)(ws + 3 * SZ_X + 2 * SZ_W);
  u16* wob  = (u16*)(ws + 3 * SZ_X + 3 * SZ_W);
  u16* Qh   = (u16*)(ws + 3 * SZ_X + 4 * SZ_W);
  u16* Kh   = (u16*)(ws + 4 * SZ_X + 4 * SZ_W);
  u16* Vt   = (u16*)(ws + 5 * SZ_X + 4 * SZ_W);
  u16* Xcat = (u16*)(ws + 6 * SZ_X + 4 * SZ_W);    // total 64 MiB

  cast_all<<<dim3(1024, 7), 256, 0, stream>>>(q, k, v, Wq, Wk, Wv, Wo,
                                              qbf, kbf, vbf, wqb, wkb, wvb, wob);

  gemm_qkv<<<dim3(MROWS / 128, EMBED / 128, 3), 256, 0, stream>>>(
      qbf, kbf, vbf, wqb, wkb, wvb, Qh, Kh, Vt);

  attn_kernel<<<dim3(SEQ / 64, BATCH * NHEAD), 256, 0, stream>>>(Qh, Kh, Vt, Xcat);

  gemm_out<<<dim3(MROWS / 64, EMBED / 128), 256, 0, stream>>>(Xcat, wob, (float*)d_out);
}

// Round 3
// 136.801 us; speedup vs baseline: 2.6502x; 2.2402x over previous
//
#include <hip/hip_runtime.h>
#include <hip/hip_bf16.h>
#include <stdint.h>

#define EMBED 1024
#define NHEAD 16
#define DKD   64
#define BATCH 2
#define SEQ   2048
#define MROWS (BATCH*SEQ)   // 4096

typedef __attribute__((ext_vector_type(8))) short bf16x8;
typedef __attribute__((ext_vector_type(4))) float f32x4;
typedef unsigned short u16;
typedef unsigned int   u32;

__device__ inline u16 f2bf(float f) {
  return __builtin_bit_cast(u16, __float2bfloat16(f));  // single v_cvt, RNE
}

__device__ inline void gload_lds16(const u16* g, u16* l) {
  __builtin_amdgcn_global_load_lds(
      (const __attribute__((address_space(1))) u32*)(const void*)g,
      (__attribute__((address_space(3))) u32*)(void*)l, 16, 0, 0);
}

// ---------------- fused cast fp32 -> bf16 (all 7 tensors, 1 launch) --------
__global__ __launch_bounds__(256) void cast_all(
    const float* __restrict__ s0, const float* __restrict__ s1,
    const float* __restrict__ s2, const float* __restrict__ s3,
    const float* __restrict__ s4, const float* __restrict__ s5,
    const float* __restrict__ s6,
    u16* __restrict__ d0, u16* __restrict__ d1, u16* __restrict__ d2,
    u16* __restrict__ d3, u16* __restrict__ d4, u16* __restrict__ d5,
    u16* __restrict__ d6) {
  const int y = blockIdx.y;
  const float* s; u16* d; int n4;
  switch (y) {
    case 0: s = s0; d = d0; n4 = MROWS*EMBED/4; break;
    case 1: s = s1; d = d1; n4 = MROWS*EMBED/4; break;
    case 2: s = s2; d = d2; n4 = MROWS*EMBED/4; break;
    case 3: s = s3; d = d3; n4 = EMBED*EMBED/4; break;
    case 4: s = s4; d = d4; n4 = EMBED*EMBED/4; break;
    case 5: s = s5; d = d5; n4 = EMBED*EMBED/4; break;
    default: s = s6; d = d6; n4 = EMBED*EMBED/4; break;
  }
  int i = blockIdx.x * 256 + threadIdx.x;
  int stride = gridDim.x * 256;
  for (int idx = i; idx < n4; idx += stride) {
    float4 f = ((const float4*)s)[idx];
    ushort4 o;
    o.x = f2bf(f.x); o.y = f2bf(f.y); o.z = f2bf(f.z); o.w = f2bf(f.w);
    ((ushort4*)d)[idx] = o;
  }
}

// ---------------- fused QKV projection GEMM (B^T), BM=128, grid.z selects --
__global__ __launch_bounds__(256)
void gemm_qkv(const u16* __restrict__ A0, const u16* __restrict__ A1,
              const u16* __restrict__ A2, const u16* __restrict__ B0,
              const u16* __restrict__ B1, const u16* __restrict__ B2,
              u16* __restrict__ C0, u16* __restrict__ C1, u16* __restrict__ C2) {
  constexpr int K = EMBED;
  __shared__ u16 As[128 * 32];
  __shared__ u16 Bs[128 * 32];
  const int z = blockIdx.z;
  const u16* A = (z == 0) ? A0 : (z == 1) ? A1 : A2;
  const u16* B = (z == 0) ? B0 : (z == 1) ? B1 : B2;
  u16* C       = (z == 0) ? C0 : (z == 1) ? C1 : C2;

  const int t = threadIdx.x;
  const int w = t >> 6, l = t & 63;
  const int lr = l & 15, lg = l >> 4;
  const int m0 = blockIdx.x * 128;
  const int n0 = blockIdx.y * 128;
  const int wr = (w >> 1) * 64, wc = (w & 1) * 64;

  f32x4 acc[4][4] = {};

  const int srow = t >> 2;
  const int scol = (t & 3) * 8;
  const u16* Ag = A + (size_t)(m0 + srow) * K + scol;
  const u16* Bg = B + (size_t)(n0 + srow) * K + scol;
  u16* AsW = As + w * 512;
  u16* BsW = Bs + w * 512;
  const size_t rowstep = (size_t)64 * K;

  for (int k0 = 0; k0 < K; k0 += 32) {
    gload_lds16(Ag + k0,           AsW);
    gload_lds16(Ag + k0 + rowstep, AsW + 64 * 32);
    gload_lds16(Bg + k0,           BsW);
    gload_lds16(Bg + k0 + rowstep, BsW + 64 * 32);
    __syncthreads();
    bf16x8 a[4], b[4];
#pragma unroll
    for (int r = 0; r < 4; r++)
      a[r] = *(const bf16x8*)(As + (wr + r * 16 + lr) * 32 + 8 * lg);
#pragma unroll
    for (int c = 0; c < 4; c++)
      b[c] = *(const bf16x8*)(Bs + (wc + c * 16 + lr) * 32 + 8 * lg);
#pragma unroll
    for (int r = 0; r < 4; r++)
#pragma unroll
      for (int c = 0; c < 4; c++)
        acc[r][c] = __builtin_amdgcn_mfma_f32_16x16x32_bf16(a[r], b[c], acc[r][c], 0, 0, 0);
    __syncthreads();
  }

#pragma unroll
  for (int r = 0; r < 4; r++)
#pragma unroll
    for (int c = 0; c < 4; c++)
#pragma unroll
      for (int j = 0; j < 4; j++) {
        int m = m0 + wr + r * 16 + lg * 4 + j;
        int n = n0 + wc + c * 16 + lr;
        int b_ = m >> 11, s_ = m & 2047;
        int h_ = n >> 6,  d_ = n & 63;
        u16 vv = f2bf(acc[r][c][j]);
        if (z == 2)
          C[((size_t)(b_ * NHEAD + h_) * DKD + d_) * SEQ + s_] = vv;   // V^T
        else
          C[(((size_t)(b_ * NHEAD + h_) * SEQ + s_) << 6) + d_] = vv;  // heads
      }
}

// ---------------- output GEMM (B^T), BM=64 x BN=128, fp32 out -------------
__global__ __launch_bounds__(256)
void gemm_out(const u16* __restrict__ A, const u16* __restrict__ B,
              float* __restrict__ C) {
  constexpr int K = EMBED, N = EMBED;
  __shared__ u16 As[64 * 32];
  __shared__ u16 Bs[128 * 32];
  const int t = threadIdx.x;
  const int w = t >> 6, l = t & 63;
  const int lr = l & 15, lg = l >> 4;
  const int m0 = blockIdx.x * 64;
  const int n0 = blockIdx.y * 128;
  const int wr = (w >> 1) * 32, wc = (w & 1) * 64;

  f32x4 acc[2][4] = {};

  const int srow = t >> 2;
  const int scol = (t & 3) * 8;
  const u16* Ag = A + (size_t)(m0 + srow) * K + scol;
  const u16* Bg = B + (size_t)(n0 + srow) * K + scol;
  u16* AsW = As + w * 512;
  u16* BsW = Bs + w * 512;
  const size_t rowstep = (size_t)64 * K;

  for (int k0 = 0; k0 < K; k0 += 32) {
    gload_lds16(Ag + k0,           AsW);
    gload_lds16(Bg + k0,           BsW);
    gload_lds16(Bg + k0 + rowstep, BsW + 64 * 32);
    __syncthreads();
    bf16x8 a[2], b[4];
#pragma unroll
    for (int r = 0; r < 2; r++)
      a[r] = *(const bf16x8*)(As + (wr + r * 16 + lr) * 32 + 8 * lg);
#pragma unroll
    for (int c = 0; c < 4; c++)
      b[c] = *(const bf16x8*)(Bs + (wc + c * 16 + lr) * 32 + 8 * lg);
#pragma unroll
    for (int r = 0; r < 2; r++)
#pragma unroll
      for (int c = 0; c < 4; c++)
        acc[r][c] = __builtin_amdgcn_mfma_f32_16x16x32_bf16(a[r], b[c], acc[r][c], 0, 0, 0);
    __syncthreads();
  }

#pragma unroll
  for (int r = 0; r < 2; r++)
#pragma unroll
    for (int c = 0; c < 4; c++)
#pragma unroll
      for (int j = 0; j < 4; j++) {
        int m = m0 + wr + r * 16 + lg * 4 + j;
        int n = n0 + wc + c * 16 + lr;
        C[(size_t)m * N + n] = acc[r][c][j];
      }
}

// ---------------- flash attention v3: swapped QK^T, per-lane softmax -------
// Qh,Kh: [B,H,S,DK] bf16; Vt: [B,H,DK,S] bf16; Xo: [B,S,E] bf16
// 4 waves x 32 q-rows = 128 q/block; KVBLK=64; K+V staged in dbuf LDS.
__global__ __launch_bounds__(256, 2)
void attn_kernel(const u16* __restrict__ Qh, const u16* __restrict__ Kh,
                 const u16* __restrict__ Vt, u16* __restrict__ Xo) {
  __shared__ u16 KV[2][8192];      // per buf: K[64][64] (8KB) then V^T[64][64] (8KB)
  __shared__ u16 Pl[4][32 * 64];   // per-wave P tile [32 q][64 kv], swizzled

  const int t = threadIdx.x, w = t >> 6, l = t & 63;
  const int lr = l & 15, lg = l >> 4;
  // XCD-clustered decode: XCD k owns bh in {4k..4k+3} (2MB K/V -> fits L2)
  const int xcd = blockIdx.x & 7;
  const int li  = blockIdx.x >> 3;          // 0..63
  const int bh  = xcd * 4 + (li >> 4);
  const int qblk = li & 15;
  const int b_ = bh >> 4, h_ = bh & 15;
  const size_t base = (size_t)bh * SEQ * DKD;
  const u16* Kb = Kh + base;
  const u16* Vb = Vt + base;                // [DK][SEQ]
  constexpr int NT = SEQ / 64;              // 32
  constexpr float C2 = 0.18033688f;         // 0.125 * log2(e)
  constexpr float THR = 44.0f;              // ~8/C2 (log2-domain bound 2^8)

  // Q fragments (B-operand): lane holds Q[q=lr][d=32ks+8lg..+7]
  bf16x8 qf[2][2];
#pragma unroll
  for (int r = 0; r < 2; r++)
#pragma unroll
    for (int ks = 0; ks < 2; ks++) {
      int qrow = qblk * 128 + w * 32 + r * 16 + lr;
      qf[r][ks] = *(const bf16x8*)(Qh + base + (size_t)qrow * DKD + ks * 32 + lg * 8);
    }

  f32x4 acc[2][4] = {};
  float m2[2] = {-1e30f, -1e30f}, lsum[2] = {0.f, 0.f};
  const int sw8  = lr & 7;       // swizzle key (row & 7 == lr & 7 everywhere)
  const int sw16 = sw8 << 4;

  u16* Pw = &Pl[w][0];

  auto stage = [&](int buf, int kt) {
    u16* kd = &KV[buf][0];
    u16* vd = &KV[buf][4096];
    const int rb = w * 8 + (l >> 3);        // wave-local row band
    const int sg = (l & 7) ^ (l >> 3);      // pre-swizzled source slot
#pragma unroll
    for (int ch = 0; ch < 2; ch++) {
      int row = ch * 32 + rb;
      gload_lds16(Kb + (size_t)(kt * 64 + row) * DKD + sg * 8,
                  kd + (ch * 32 + w * 8) * 64);
      gload_lds16(Vb + (size_t)row * SEQ + kt * 64 + sg * 8,
                  vd + (ch * 32 + w * 8) * 64);
    }
  };

  auto compute = [&](int buf) {
    const u16* kd = &KV[buf][0];
    const u16* vd = &KV[buf][4096];
    // ---- QK^T swapped: s[r][c] holds S^T[kv][q], lane: q=lr, kv=c*16+4*lg+j
    f32x4 s[2][4] = {};
#pragma unroll
    for (int c = 0; c < 4; c++) {
      int row = c * 16 + lr;
      bf16x8 k0 = *(const bf16x8*)(kd + row * 64 + ((lg)     ^ sw8) * 8);
      bf16x8 k1 = *(const bf16x8*)(kd + row * 64 + ((lg + 4) ^ sw8) * 8);
#pragma unroll
      for (int r = 0; r < 2; r++) {
        s[r][c] = __builtin_amdgcn_mfma_f32_16x16x32_bf16(k0, qf[r][0], s[r][c], 0, 0, 0);
        s[r][c] = __builtin_amdgcn_mfma_f32_16x16x32_bf16(k1, qf[r][1], s[r][c], 0, 0, 0);
      }
    }
    // ---- in-lane max (raw score domain), deferred rescale
    float pm[2];
#pragma unroll
    for (int r = 0; r < 2; r++) {
      float a = fmaxf(fmaxf(s[r][0][0], s[r][0][1]), fmaxf(s[r][0][2], s[r][0][3]));
      float b = fmaxf(fmaxf(s[r][1][0], s[r][1][1]), fmaxf(s[r][1][2], s[r][1][3]));
      float c = fmaxf(fmaxf(s[r][2][0], s[r][2][1]), fmaxf(s[r][2][2], s[r][2][3]));
      float d = fmaxf(fmaxf(s[r][3][0], s[r][3][1]), fmaxf(s[r][3][2], s[r][3][3]));
      pm[r] = fmaxf(fmaxf(a, b), fmaxf(c, d));
    }
    int trig = (pm[0] > m2[0] + THR) | (pm[1] > m2[1] + THR);
    if (__any(trig)) {
#pragma unroll
      for (int r = 0; r < 2; r++) {
        float pr = fmaxf(pm[r], __shfl_xor(pm[r], 16, 64));
        pr = fmaxf(pr, __shfl_xor(pr, 32, 64));
        float mn = fmaxf(m2[r], pr);
        float al = __builtin_amdgcn_exp2f((m2[r] - mn) * C2);
        lsum[r] *= al;
        m2[r] = mn;
        float alj[4];
#pragma unroll
        for (int j = 0; j < 4; j++) alj[j] = __shfl(al, 4 * lg + j, 64);
#pragma unroll
        for (int n = 0; n < 4; n++)
#pragma unroll
          for (int j = 0; j < 4; j++) acc[r][n][j] *= alj[j];
      }
    }
    // ---- P = exp2((s - m2)*C2), per-lane partial sum, pack -> LDS
#pragma unroll
    for (int r = 0; r < 2; r++) {
      float nm2c = -m2[r] * C2;
      char* prow = (char*)(Pw + (r * 16 + lr) * 64);
      float ls = 0.f;
#pragma unroll
      for (int c = 0; c < 4; c++) {
        float p0 = __builtin_amdgcn_exp2f(__builtin_fmaf(s[r][c][0], C2, nm2c));
        float p1 = __builtin_amdgcn_exp2f(__builtin_fmaf(s[r][c][1], C2, nm2c));
        float p2 = __builtin_amdgcn_exp2f(__builtin_fmaf(s[r][c][2], C2, nm2c));
        float p3 = __builtin_amdgcn_exp2f(__builtin_fmaf(s[r][c][3], C2, nm2c));
        ls += (p0 + p1) + (p2 + p3);
        u32 lo = (u32)f2bf(p0) | ((u32)f2bf(p1) << 16);
        u32 hi = (u32)f2bf(p2) | ((u32)f2bf(p3) << 16);
        uint2 pk; pk.x = lo; pk.y = hi;
        *(uint2*)(prow + ((32 * c + 8 * lg) ^ sw16)) = pk;
      }
      lsum[r] += ls;
    }
    // ---- PV: A = P fragments (repacked via LDS), B = V^T from LDS
    bf16x8 pf[2][2];
#pragma unroll
    for (int r = 0; r < 2; r++) {
      char* prow = (char*)(Pw + (r * 16 + lr) * 64);
#pragma unroll
      for (int ks = 0; ks < 2; ks++)
        pf[r][ks] = *(const bf16x8*)(prow + ((64 * ks + 16 * lg) ^ sw16));
    }
#pragma unroll
    for (int ks = 0; ks < 2; ks++)
#pragma unroll
      for (int n = 0; n < 4; n++) {
        bf16x8 vf = *(const bf16x8*)(vd + (n * 16 + lr) * 64 + ((lg + 4 * ks) ^ sw8) * 8);
#pragma unroll
        for (int r = 0; r < 2; r++)
          acc[r][n] = __builtin_amdgcn_mfma_f32_16x16x32_bf16(pf[r][ks], vf, acc[r][n], 0, 0, 0);
      }
  };

  stage(0, 0);
  __syncthreads();
  int cur = 0;
  for (int kt = 0; kt < NT; kt++) {
    if (kt + 1 < NT) stage(cur ^ 1, kt + 1);
    compute(cur);
    __syncthreads();
    cur ^= 1;
  }

  // ---- epilogue: final cross-lane l reduce, normalize, store
#pragma unroll
  for (int r = 0; r < 2; r++) {
    float lv = lsum[r];
    lv += __shfl_xor(lv, 16, 64);
    lv += __shfl_xor(lv, 32, 64);
    float inv = 1.0f / lv;
    float invj[4];
#pragma unroll
    for (int j = 0; j < 4; j++) invj[j] = __shfl(inv, 4 * lg + j, 64);
#pragma unroll
    for (int n = 0; n < 4; n++)
#pragma unroll
      for (int j = 0; j < 4; j++) {
        int q = qblk * 128 + w * 32 + r * 16 + 4 * lg + j;
        Xo[((size_t)b_ * SEQ + q) * EMBED + h_ * DKD + n * 16 + lr] =
            f2bf(acc[r][n][j] * invj[j]);
      }
  }
}

extern "C" void kernel_launch(void* const* d_in, const int* in_sizes, int n_in,
                              void* d_out, int out_size, void* d_ws, size_t ws_size,
                              hipStream_t stream) {
  const float* q  = (const float*)d_in[0];
  const float* k  = (const float*)d_in[1];
  const float* v  = (const float*)d_in[2];
  const float* Wq = (const float*)d_in[3];
  const float* Wk = (const float*)d_in[4];
  const float* Wv = (const float*)d_in[5];
  const float* Wo = (const float*)d_in[6];

  char* ws = (char*)d_ws;
  const size_t SZ_X = (size_t)MROWS * EMBED * 2;   // 8 MiB
  const size_t SZ_W = (size_t)EMBED * EMBED * 2;   // 2 MiB
  u16* qbf  = (u16*)(ws);
  u16* kbf  = (u16*)(ws + SZ_X);
  u16* vbf  = (u16*)(ws + 2 * SZ_X);
  u16* wqb  = (u16*)(ws + 3 * SZ_X);
  u16* wkb  = (u16*)(ws + 3 * SZ_X + SZ_W);
  u16* wvb  = (u16*)(ws + 3 * SZ_X + 2 * SZ_W);
  u16* wob  = (u16*)(ws + 3 * SZ_X + 3 * SZ_W);
  u16* Qh   = (u16*)(ws + 3 * SZ_X + 4 * SZ_W);
  u16* Kh   = (u16*)(ws + 4 * SZ_X + 4 * SZ_W);
  u16* Vt   = (u16*)(ws + 5 * SZ_X + 4 * SZ_W);
  u16* Xcat = (u16*)(ws + 6 * SZ_X + 4 * SZ_W);    // total 64 MiB

  cast_all<<<dim3(1024, 7), 256, 0, stream>>>(q, k, v, Wq, Wk, Wv, Wo,
                                              qbf, kbf, vbf, wqb, wkb, wvb, wob);

  gemm_qkv<<<dim3(MROWS / 128, EMBED / 128, 3), 256, 0, stream>>>(
      qbf, kbf, vbf, wqb, wkb, wvb, Qh, Kh, Vt);

  attn_kernel<<<512, 256, 0, stream>>>(Qh, Kh, Vt, Xcat);

  gemm_out<<<dim3(MROWS / 64, EMBED / 128), 256, 0, stream>>>(Xcat, wob, (float*)d_out);
}

// Round 4
// 122.375 us; speedup vs baseline: 2.9626x; 1.1179x over previous
//
#include <hip/hip_runtime.h>
#include <hip/hip_bf16.h>
#include <stdint.h>

#define EMBED 1024
#define NHEAD 16
#define DKD   64
#define BATCH 2
#define SEQ   2048
#define MROWS (BATCH*SEQ)   // 4096

typedef __attribute__((ext_vector_type(8)))  short bf16x8;
typedef __attribute__((ext_vector_type(4)))  float f32x4;
typedef __attribute__((ext_vector_type(16))) float f32x16;
typedef unsigned short u16;
typedef unsigned int   u32;
typedef __attribute__((ext_vector_type(4))) u32 u32x4;

__device__ inline u16 f2bf(float f) {
  return __builtin_bit_cast(u16, __float2bfloat16(f));  // single v_cvt, RNE
}

__device__ inline u32 cvtpk(float lo, float hi) {   // lo->bits[15:0], hi->bits[31:16]
  u32 r;
  asm("v_cvt_pk_bf16_f32 %0, %1, %2" : "=v"(r) : "v"(lo), "v"(hi));
  return r;
}

// X' = (h0: X_h0, h1: Y_h0) ; Y' = (h0: X_h1, h1: Y_h1)   [vdst.row1 <-> vsrc.row0]
__device__ inline void plswap(u32& x, u32& y) {
  asm volatile("v_permlane32_swap_b32 %0, %1" : "+v"(x), "+v"(y));
}

__device__ inline void gload_lds16(const u16* g, u16* l) {
  __builtin_amdgcn_global_load_lds(
      (const __attribute__((address_space(1))) u32*)(const void*)g,
      (__attribute__((address_space(3))) u32*)(void*)l, 16, 0, 0);
}

// ---------------- fused cast fp32 -> bf16 (all 7 tensors, 1 launch) --------
__global__ __launch_bounds__(256) void cast_all(
    const float* __restrict__ s0, const float* __restrict__ s1,
    const float* __restrict__ s2, const float* __restrict__ s3,
    const float* __restrict__ s4, const float* __restrict__ s5,
    const float* __restrict__ s6,
    u16* __restrict__ d0, u16* __restrict__ d1, u16* __restrict__ d2,
    u16* __restrict__ d3, u16* __restrict__ d4, u16* __restrict__ d5,
    u16* __restrict__ d6) {
  const int y = blockIdx.y;
  const float* s; u16* d; int n4;
  switch (y) {
    case 0: s = s0; d = d0; n4 = MROWS*EMBED/4; break;
    case 1: s = s1; d = d1; n4 = MROWS*EMBED/4; break;
    case 2: s = s2; d = d2; n4 = MROWS*EMBED/4; break;
    case 3: s = s3; d = d3; n4 = EMBED*EMBED/4; break;
    case 4: s = s4; d = d4; n4 = EMBED*EMBED/4; break;
    case 5: s = s5; d = d5; n4 = EMBED*EMBED/4; break;
    default: s = s6; d = d6; n4 = EMBED*EMBED/4; break;
  }
  int i = blockIdx.x * 256 + threadIdx.x;
  int stride = gridDim.x * 256;
  for (int idx = i; idx < n4; idx += stride) {
    float4 f = ((const float4*)s)[idx];
    ushort4 o;
    o.x = f2bf(f.x); o.y = f2bf(f.y); o.z = f2bf(f.z); o.w = f2bf(f.w);
    ((ushort4*)d)[idx] = o;
  }
}

// ---------------- fused QKV projection GEMM (B^T), BM=128, grid.z selects --
__global__ __launch_bounds__(256)
void gemm_qkv(const u16* __restrict__ A0, const u16* __restrict__ A1,
              const u16* __restrict__ A2, const u16* __restrict__ B0,
              const u16* __restrict__ B1, const u16* __restrict__ B2,
              u16* __restrict__ C0, u16* __restrict__ C1, u16* __restrict__ C2) {
  constexpr int K = EMBED;
  __shared__ u16 As[128 * 32];
  __shared__ u16 Bs[128 * 32];
  const int z = blockIdx.z;
  const u16* A = (z == 0) ? A0 : (z == 1) ? A1 : A2;
  const u16* B = (z == 0) ? B0 : (z == 1) ? B1 : B2;
  u16* C       = (z == 0) ? C0 : (z == 1) ? C1 : C2;

  const int t = threadIdx.x;
  const int w = t >> 6, l = t & 63;
  const int lr = l & 15, lg = l >> 4;
  const int m0 = blockIdx.x * 128;
  const int n0 = blockIdx.y * 128;
  const int wr = (w >> 1) * 64, wc = (w & 1) * 64;

  f32x4 acc[4][4] = {};

  const int srow = t >> 2;
  const int scol = (t & 3) * 8;
  const u16* Ag = A + (size_t)(m0 + srow) * K + scol;
  const u16* Bg = B + (size_t)(n0 + srow) * K + scol;
  u16* AsW = As + w * 512;
  u16* BsW = Bs + w * 512;
  const size_t rowstep = (size_t)64 * K;

  for (int k0 = 0; k0 < K; k0 += 32) {
    gload_lds16(Ag + k0,           AsW);
    gload_lds16(Ag + k0 + rowstep, AsW + 64 * 32);
    gload_lds16(Bg + k0,           BsW);
    gload_lds16(Bg + k0 + rowstep, BsW + 64 * 32);
    __syncthreads();
    bf16x8 a[4], b[4];
#pragma unroll
    for (int r = 0; r < 4; r++)
      a[r] = *(const bf16x8*)(As + (wr + r * 16 + lr) * 32 + 8 * lg);
#pragma unroll
    for (int c = 0; c < 4; c++)
      b[c] = *(const bf16x8*)(Bs + (wc + c * 16 + lr) * 32 + 8 * lg);
#pragma unroll
    for (int r = 0; r < 4; r++)
#pragma unroll
      for (int c = 0; c < 4; c++)
        acc[r][c] = __builtin_amdgcn_mfma_f32_16x16x32_bf16(a[r], b[c], acc[r][c], 0, 0, 0);
    __syncthreads();
  }

#pragma unroll
  for (int r = 0; r < 4; r++)
#pragma unroll
    for (int c = 0; c < 4; c++)
#pragma unroll
      for (int j = 0; j < 4; j++) {
        int m = m0 + wr + r * 16 + lg * 4 + j;
        int n = n0 + wc + c * 16 + lr;
        int b_ = m >> 11, s_ = m & 2047;
        int h_ = n >> 6,  d_ = n & 63;
        u16 vv = f2bf(acc[r][c][j]);
        if (z == 2)
          C[((size_t)(b_ * NHEAD + h_) * DKD + d_) * SEQ + s_] = vv;   // V^T
        else
          C[(((size_t)(b_ * NHEAD + h_) * SEQ + s_) << 6) + d_] = vv;  // heads
      }
}

// ---------------- output GEMM (B^T), BM=64 x BN=128, fp32 out -------------
__global__ __launch_bounds__(256)
void gemm_out(const u16* __restrict__ A, const u16* __restrict__ B,
              float* __restrict__ C) {
  constexpr int K = EMBED, N = EMBED;
  __shared__ u16 As[64 * 32];
  __shared__ u16 Bs[128 * 32];
  const int t = threadIdx.x;
  const int w = t >> 6, l = t & 63;
  const int lr = l & 15, lg = l >> 4;
  const int m0 = blockIdx.x * 64;
  const int n0 = blockIdx.y * 128;
  const int wr = (w >> 1) * 32, wc = (w & 1) * 64;

  f32x4 acc[2][4] = {};

  const int srow = t >> 2;
  const int scol = (t & 3) * 8;
  const u16* Ag = A + (size_t)(m0 + srow) * K + scol;
  const u16* Bg = B + (size_t)(n0 + srow) * K + scol;
  u16* AsW = As + w * 512;
  u16* BsW = Bs + w * 512;
  const size_t rowstep = (size_t)64 * K;

  for (int k0 = 0; k0 < K; k0 += 32) {
    gload_lds16(Ag + k0,           AsW);
    gload_lds16(Bg + k0,           BsW);
    gload_lds16(Bg + k0 + rowstep, BsW + 64 * 32);
    __syncthreads();
    bf16x8 a[2], b[4];
#pragma unroll
    for (int r = 0; r < 2; r++)
      a[r] = *(const bf16x8*)(As + (wr + r * 16 + lr) * 32 + 8 * lg);
#pragma unroll
    for (int c = 0; c < 4; c++)
      b[c] = *(const bf16x8*)(Bs + (wc + c * 16 + lr) * 32 + 8 * lg);
#pragma unroll
    for (int r = 0; r < 2; r++)
#pragma unroll
      for (int c = 0; c < 4; c++)
        acc[r][c] = __builtin_amdgcn_mfma_f32_16x16x32_bf16(a[r], b[c], acc[r][c], 0, 0, 0);
    __syncthreads();
  }

#pragma unroll
  for (int r = 0; r < 2; r++)
#pragma unroll
    for (int c = 0; c < 4; c++)
#pragma unroll
      for (int j = 0; j < 4; j++) {
        int m = m0 + wr + r * 16 + lg * 4 + j;
        int n = n0 + wc + c * 16 + lr;
        C[(size_t)m * N + n] = acc[r][c][j];
      }
}

// ---------------- flash attention v4: 32x32 MFMA, all-register softmax -----
// Swapped QK^T (lane q = l&31 owns a full score row) + swapped PV (acc = O^T,
// state lane-local) + cvt_pk/permlane32_swap P-repack (zero P LDS traffic).
// Qh,Kh: [B,H,S,DK] bf16; Vt: [B,H,DK,S] bf16; Xo: [B,S,E] bf16
__global__ __launch_bounds__(256, 2)
void attn_kernel(const u16* __restrict__ Qh, const u16* __restrict__ Kh,
                 const u16* __restrict__ Vt, u16* __restrict__ Xo) {
  __shared__ u16 KV[2][8192];      // per buf: K[64 kv][64 d] | V^T[64 d][64 kv], XOR-swizzled
  const int t = threadIdx.x, w = t >> 6, l = t & 63;
  const int q32 = l & 31, h = l >> 5;
  // XCD-clustered decode: XCD k owns bh in {4k..4k+3}
  const int xcd = blockIdx.x & 7;
  const int li  = blockIdx.x >> 3;          // 0..63
  const int bh  = xcd * 4 + (li >> 4);
  const int qblk = li & 15;
  const int b_ = bh >> 4, h_ = bh & 15;
  const size_t base = (size_t)bh * SEQ * DKD;
  const u16* Kb = Kh + base;
  const u16* Vb = Vt + base;                // [DK][SEQ]
  constexpr int NT = SEQ / 64;              // 32
  constexpr float C2 = 0.18033688f;         // 0.125 * log2(e)
  constexpr float THR = 44.0f;              // raw-domain defer-max bound (~2^8)

  // Q fragments (B-operand, 32x32x16): lane holds Q[q=q32][d=16ks+8h+e]
  const int qrow = qblk * 128 + w * 32 + q32;
  bf16x8 qf[4];
#pragma unroll
  for (int ks = 0; ks < 4; ks++)
    qf[ks] = *(const bf16x8*)(Qh + base + (size_t)qrow * DKD + ks * 16 + h * 8);

  f32x16 acc[2] = {};                       // O^T: lane q=q32, d=(r&3)+8(r>>2)+4h+32dc
  float m2 = -1e30f, lsum = 0.f;

  auto stage = [&](int buf, int kt) {
    u16* kd = &KV[buf][0];
    u16* vd = &KV[buf][4096];
    const int rb = w * 8 + (l >> 3);        // wave-local row band
    const int sg = (l & 7) ^ (l >> 3);      // pre-swizzled source slot
#pragma unroll
    for (int ch = 0; ch < 2; ch++) {
      int row = ch * 32 + rb;
      gload_lds16(Kb + (size_t)(kt * 64 + row) * DKD + sg * 8,
                  kd + (ch * 32 + w * 8) * 64);
      gload_lds16(Vb + (size_t)row * SEQ + kt * 64 + sg * 8,
                  vd + (ch * 32 + w * 8) * 64);
    }
  };

  auto compute = [&](int buf) {
    const u16* kd = &KV[buf][0];
    const u16* vd = &KV[buf][4096];
    // ---- QK^T swapped: s[c] = S^T[kv=c*32+(r&3)+8(r>>2)+4h][q=q32]
    f32x16 s[2] = {};
#pragma unroll
    for (int c = 0; c < 2; c++) {
      int row = c * 32 + q32;
#pragma unroll
      for (int ks = 0; ks < 4; ks++) {
        bf16x8 kf = *(const bf16x8*)(kd + row * 64 + (((2 * ks + h) ^ (row & 7)) * 8));
        s[c] = __builtin_amdgcn_mfma_f32_32x32x16_bf16(kf, qf[ks], s[c], 0, 0, 0);
      }
    }
    // ---- V fragments early (hide ds latency under softmax VALU)
    bf16x8 vf[2][4];
#pragma unroll
    for (int dc = 0; dc < 2; dc++) {
      int row = dc * 32 + q32;
#pragma unroll
      for (int tile = 0; tile < 4; tile++)
        vf[dc][tile] = *(const bf16x8*)(vd + row * 64 + (((2 * tile + h) ^ (row & 7)) * 8));
    }
    // ---- per-lane max over this tile's 32 scores (raw domain)
    float pm = s[0][0];
#pragma unroll
    for (int r = 1; r < 16; r++) pm = fmaxf(pm, s[0][r]);
#pragma unroll
    for (int r = 0; r < 16; r++) pm = fmaxf(pm, s[1][r]);
    if (__any(pm > m2 + THR)) {             // defer-max trigger (rare)
      float pmo = __shfl_xor(pm, 32, 64);   // true row max needs both halves
      float mn = fmaxf(m2, fmaxf(pm, pmo));
      float al = __builtin_amdgcn_exp2f((m2 - mn) * C2);
      lsum *= al;
#pragma unroll
      for (int dc = 0; dc < 2; dc++)
#pragma unroll
        for (int r = 0; r < 16; r++) acc[dc][r] *= al;
      m2 = mn;
    }
    // ---- P = exp2((s-m)*C2); pack + permlane-swap into PV B-fragments
    const float nm = -m2 * C2;
    bf16x8 pfrag[4];
    float ls = 0.f;
#pragma unroll
    for (int c = 0; c < 2; c++) {
      float p[16];
#pragma unroll
      for (int r = 0; r < 16; r++) {
        p[r] = __builtin_amdgcn_exp2f(__builtin_fmaf(s[c][r], C2, nm));
        ls += p[r];
      }
      u32 Pk[8];
#pragma unroll
      for (int i = 0; i < 8; i++) Pk[i] = cvtpk(p[2 * i], p[2 * i + 1]);
      plswap(Pk[0], Pk[2]); plswap(Pk[1], Pk[3]);
      plswap(Pk[4], Pk[6]); plswap(Pk[5], Pk[7]);
      pfrag[2 * c]     = __builtin_bit_cast(bf16x8, (u32x4){Pk[0], Pk[1], Pk[2], Pk[3]});
      pfrag[2 * c + 1] = __builtin_bit_cast(bf16x8, (u32x4){Pk[4], Pk[5], Pk[6], Pk[7]});
    }
    lsum += ls;
    // ---- PV swapped: acc[dc] += V^T-frag x P-frag  (D = O^T)
#pragma unroll
    for (int tile = 0; tile < 4; tile++)
#pragma unroll
      for (int dc = 0; dc < 2; dc++)
        acc[dc] = __builtin_amdgcn_mfma_f32_32x32x16_bf16(vf[dc][tile], pfrag[tile], acc[dc], 0, 0, 0);
  };

  stage(0, 0);
  __syncthreads();
  int cur = 0;
  for (int kt = 0; kt < NT; kt++) {
    if (kt + 1 < NT) stage(cur ^ 1, kt + 1);
    compute(cur);
    __syncthreads();
    cur ^= 1;
  }

  // ---- epilogue: combine halves' lsum, normalize (all lane-local), store
  lsum += __shfl_xor(lsum, 32, 64);
  float inv = 1.0f / lsum;
  u16* orow = Xo + ((size_t)b_ * SEQ + qrow) * EMBED + h_ * DKD;
#pragma unroll
  for (int dc = 0; dc < 2; dc++)
#pragma unroll
    for (int k4 = 0; k4 < 4; k4++) {
      u32 w0 = cvtpk(acc[dc][4 * k4 + 0] * inv, acc[dc][4 * k4 + 1] * inv);
      u32 w1 = cvtpk(acc[dc][4 * k4 + 2] * inv, acc[dc][4 * k4 + 3] * inv);
      int d = dc * 32 + k4 * 8 + h * 4;
      uint2 pk; pk.x = w0; pk.y = w1;
      *(uint2*)(orow + d) = pk;
    }
}

extern "C" void kernel_launch(void* const* d_in, const int* in_sizes, int n_in,
                              void* d_out, int out_size, void* d_ws, size_t ws_size,
                              hipStream_t stream) {
  const float* q  = (const float*)d_in[0];
  const float* k  = (const float*)d_in[1];
  const float* v  = (const float*)d_in[2];
  const float* Wq = (const float*)d_in[3];
  const float* Wk = (const float*)d_in[4];
  const float* Wv = (const float*)d_in[5];
  const float* Wo = (const float*)d_in[6];

  char* ws = (char*)d_ws;
  const size_t SZ_X = (size_t)MROWS * EMBED * 2;   // 8 MiB
  const size_t SZ_W = (size_t)EMBED * EMBED * 2;   // 2 MiB
  u16* qbf  = (u16*)(ws);
  u16* kbf  = (u16*)(ws + SZ_X);
  u16* vbf  = (u16*)(ws + 2 * SZ_X);
  u16* wqb  = (u16*)(ws + 3 * SZ_X);
  u16* wkb  = (u16*)(ws + 3 * SZ_X + SZ_W);
  u16* wvb  = (u16*)(ws + 3 * SZ_X + 2 * SZ_W);
  u16* wob  = (u16*)(ws + 3 * SZ_X + 3 * SZ_W);
  u16* Qh   = (u16*)(ws + 3 * SZ_X + 4 * SZ_W);
  u16* Kh   = (u16*)(ws + 4 * SZ_X + 4 * SZ_W);
  u16* Vt   = (u16*)(ws + 5 * SZ_X + 4 * SZ_W);
  u16* Xcat = (u16*)(ws + 6 * SZ_X + 4 * SZ_W);    // total 64 MiB

  cast_all<<<dim3(1024, 7), 256, 0, stream>>>(q, k, v, Wq, Wk, Wv, Wo,
                                              qbf, kbf, vbf, wqb, wkb, wvb, wob);

  gemm_qkv<<<dim3(MROWS / 128, EMBED / 128, 3), 256, 0, stream>>>(
      qbf, kbf, vbf, wqb, wkb, wvb, Qh, Kh, Vt);

  attn_kernel<<<512, 256, 0, stream>>>(Qh, Kh, Vt, Xcat);

  gemm_out<<<dim3(MROWS / 64, EMBED / 128), 256, 0, stream>>>(Xcat, wob, (float*)d_out);
}